// Round 1
// baseline (50046.420 us; speedup 1.0000x reference)
//
#include <hip/hip_runtime.h>

// Leaky-RNN scan: h_t = relu(0.9 h + 0.1 (W_hh h + W_in x_t + b_in + b_hh + 0.05 nz_t))
// T=4096, B=32, IN=128, H=512, fp32.
//
// Design: 16 groups x 8 slice-WGs (=128 blocks, 512 thr). Each WG keeps a
// 64-row fp32 slice of W_hh (64 VGPR/thr) + W_in slice (16 VGPR/thr) in
// registers. Per step each WG computes its 64 rows for 2 interleaved batches,
// publishes them via a parity-double-buffered global exchange buffer (d_ws)
// with agent-scope release/acquire flags. blockIdx mapping keeps each group's
// 8 WGs on one XCD (blockIdx % 8 heuristic) for L2-local exchange; only
// performance depends on that, not correctness.
//
// Flag values are "last completed step t" (monotone). d_ws is poisoned to
// 0xAAAAAAAA each launch = negative int => "nothing done" => no init needed.
// Parity double-buffering of h_ex makes writer-overtakes-reader impossible:
// a producer at step t' needs all flags >= t'-1, so it can lead the slowest
// consumer by at most one step, and writes the opposite parity.

#define T_STEPS   4096
#define NBATCH    32
#define IN_DIM    128
#define HID       512
#define NSLICES   8
#define SLICE_ROWS 64          // HID / NSLICES
#define BG        2            // batches interleaved per group
#define NGROUPS   16           // NBATCH / BG
#define NBLOCKS   (NGROUPS * NSLICES)   // 128
#define NTHREADS  512
#define ALPHA     0.1f
#define NSCALE    0.05f

__global__ __launch_bounds__(NTHREADS, 1)
void rnn_scan(const float* __restrict__ x,      // [T][B][IN]
              const float* __restrict__ W_in,   // [H][IN]
              const float* __restrict__ b_in,   // [H]
              const float* __restrict__ W_hh,   // [H][H]
              const float* __restrict__ b_hh,   // [H]
              const float* __restrict__ noise,  // [T][H]
              float* __restrict__ out,          // [T][B][H]
              float* h_ex,                      // ws: [2][B][H]
              int*   flags)                     // ws: [B][NSLICES]
{
    const int bx  = blockIdx.x;
    const int c   = bx & 7;            // XCD residue (placement heuristic)
    const int j_  = bx >> 3;           // 0..15
    const int s   = j_ & 7;            // row-slice 0..7
    const int g   = c + 8 * (j_ >> 3); // group 0..15 (all 8 slices share residue c)
    const int b0  = 2 * g;
    const int b1  = b0 + 1;

    const int tid = threadIdx.x;
    const int w   = tid >> 6;          // wave 0..7  = K-chunk
    const int l   = tid & 63;          // lane       = row within slice
    const int R   = s * SLICE_ROWS + l;   // global output row
    const int kc  = w * 64;            // W_hh K-chunk base (8 x 64 = 512)
    const int kin = w * 16;            // W_in K-chunk base (8 x 16 = 128)

    // ---- load weight slices into registers (one-time) ----
    float wh[64];
    {
        const float* whp = &W_hh[(size_t)R * HID + kc];
        #pragma unroll
        for (int q = 0; q < 64; q += 4) {
            const float4 v = *reinterpret_cast<const float4*>(whp + q);
            wh[q] = v.x; wh[q + 1] = v.y; wh[q + 2] = v.z; wh[q + 3] = v.w;
        }
    }
    float wi[16];
    {
        const float* wip = &W_in[(size_t)R * IN_DIM + kin];
        #pragma unroll
        for (int q = 0; q < 16; q += 4) {
            const float4 v = *reinterpret_cast<const float4*>(wip + q);
            wi[q] = v.x; wi[q + 1] = v.y; wi[q + 2] = v.z; wi[q + 3] = v.w;
        }
    }

    // owner state: wave 0 owns batch b0's rows, wave 1 owns b1's rows
    float hprev  = 0.0f;
    float bconst = 0.0f;
    if (w < BG) bconst = b_hh[R] + b_in[R];

    __shared__ __align__(16) float lds_h[BG][HID];          // staged h_{t-1}
    __shared__ float lds_part[BG][NSLICES][SLICE_ROWS];     // cross-wave partials

    const int myb[BG] = { b0, b1 };
    int deadman = 0;   // global spin budget: bounded even if something goes wrong

    for (int t = 0; t < T_STEPS; ++t) {
        // ---- prefetch x chunks early (wave-uniform addresses, 1 req each) ----
        float4 xv[BG][4];
        #pragma unroll
        for (int bi = 0; bi < BG; ++bi) {
            const float* xp = &x[((size_t)t * NBATCH + myb[bi]) * IN_DIM + kin];
            #pragma unroll
            for (int q = 0; q < 4; ++q)
                xv[bi][q] = reinterpret_cast<const float4*>(xp)[q];
        }

        // ---- wait for producers of our K-chunk, stage h_{t-1} into LDS ----
        if (t > 0) {
            const int need = t - 1;
            #pragma unroll
            for (int bi = 0; bi < BG; ++bi) {
                const int b = myb[bi];
                while (deadman < (1 << 24)) {
                    if (__hip_atomic_load(&flags[b * NSLICES + w], __ATOMIC_RELAXED,
                                          __HIP_MEMORY_SCOPE_AGENT) >= need) break;
                    ++deadman;
                }
            }
            __builtin_amdgcn_fence(__ATOMIC_ACQUIRE, "agent");
            const size_t par = ((size_t)((t - 1) & 1)) * NBATCH * HID;
            #pragma unroll
            for (int bi = 0; bi < BG; ++bi)
                lds_h[bi][kc + l] = h_ex[par + (size_t)myb[bi] * HID + kc + l];
        }

        // ---- partial dot products: 64 (W_hh) + 16 (W_in) FMAs per batch ----
        #pragma unroll
        for (int bi = 0; bi < BG; ++bi) {
            float a0 = 0.f, a1 = 0.f, a2 = 0.f, a3 = 0.f;
            if (t > 0) {
                #pragma unroll
                for (int q = 0; q < 64; q += 4) {
                    // wave-uniform LDS read -> broadcast, no bank conflict
                    const float4 hv = *reinterpret_cast<const float4*>(&lds_h[bi][kc + q]);
                    a0 = fmaf(wh[q + 0], hv.x, a0);
                    a1 = fmaf(wh[q + 1], hv.y, a1);
                    a2 = fmaf(wh[q + 2], hv.z, a2);
                    a3 = fmaf(wh[q + 3], hv.w, a3);
                }
            }
            #pragma unroll
            for (int q = 0; q < 16; q += 4) {
                const float4 v = xv[bi][q >> 2];
                a0 = fmaf(wi[q + 0], v.x, a0);
                a1 = fmaf(wi[q + 1], v.y, a1);
                a2 = fmaf(wi[q + 2], v.z, a2);
                a3 = fmaf(wi[q + 3], v.w, a3);
            }
            lds_part[bi][w][l] = (a0 + a1) + (a2 + a3);
        }
        __syncthreads();

        // ---- owner waves reduce 8 partials, update h, publish ----
        if (w < BG) {
            const int bi = w;
            const int b  = myb[bi];
            float tot = 0.f;
            #pragma unroll
            for (int q = 0; q < NSLICES; ++q)
                tot += lds_part[bi][q][l];   // bank l%32, 2-way -> free
            const float nz = noise[(size_t)t * HID + R];
            float hn = fmaf(1.0f - ALPHA, hprev, ALPHA * (tot + bconst + NSCALE * nz));
            hn = fmaxf(hn, 0.0f);
            hprev = hn;
            h_ex[((size_t)(t & 1)) * NBATCH * HID + (size_t)b * HID + R] = hn;
            out[((size_t)t * NBATCH + b) * HID + R] = hn;
            // release: drain this wave's stores (vmcnt) + L2 writeback, then flag
            __builtin_amdgcn_fence(__ATOMIC_RELEASE, "agent");
            if (l == 0)
                __hip_atomic_store(&flags[b * NSLICES + s], t, __ATOMIC_RELAXED,
                                   __HIP_MEMORY_SCOPE_AGENT);
        }
        __syncthreads();   // protect lds_part against next step's overwrite
    }
}

extern "C" void kernel_launch(void* const* d_in, const int* in_sizes, int n_in,
                              void* d_out, int out_size, void* d_ws, size_t ws_size,
                              hipStream_t stream) {
    (void)in_sizes; (void)n_in; (void)out_size; (void)ws_size;
    const float* x     = (const float*)d_in[0];
    const float* W_in  = (const float*)d_in[1];
    const float* b_in  = (const float*)d_in[2];
    const float* W_hh  = (const float*)d_in[3];
    const float* b_hh  = (const float*)d_in[4];
    const float* noise = (const float*)d_in[5];
    float* out  = (float*)d_out;
    float* h_ex = (float*)d_ws;                                   // 2*32*512 floats
    int*   flg  = (int*)((char*)d_ws + 2 * NBATCH * HID * sizeof(float)); // 32*8 ints

    hipLaunchKernelGGL(rnn_scan, dim3(NBLOCKS), dim3(NTHREADS), 0, stream,
                       x, W_in, b_in, W_hh, b_hh, noise, out, h_ex, flg);
}

// Round 6
// 13743.622 us; speedup vs baseline: 3.6414x; 3.6414x over previous
//
#include <hip/hip_runtime.h>

// Leaky-RNN scan: h_t = relu(0.9 h + 0.1 (W_hh h + W_in x_t + b_in + b_hh + 0.05 nz_t))
// T=4096, B=32, IN=128, H=512, fp32.
//
// pre_kernel: pre[t][b][h] = W_in·x + b_in + b_hh + 0.05*noise, IN-PLACE into
//   d_out (time-parallel, all CUs, ~150 us).
// rnn_scan: 16 groups x 4 row-slice blocks (64 blocks x 512 thr, 1 block/CU).
//   fp32 W_hh (1 MB) can never fit one CU's 512 KB register file -> 4-CU
//   row-split is mandatory. Each block holds rows [128s,128s+128) in regs.
//   PER-THREAD W TILE IS 4 ROWS x 32 COLS (128 VGPR): each 32-float h-chunk
//   LDS read is amortized over 4 rows -> 64 ds_read_b128 per phase per CU
//   (vs 256 for 1x128 tiling, which is LDS-return-bandwidth bound: a b128
//   broadcast still writes 64 lanes x 16 B of RF = full return cost).
//   Per step, 2 batches interleaved. ALL cross-block traffic uses RELAXED
//   AGENT-scope atomic loads/stores -> sc1-flagged global ops routed past the
//   non-coherent per-XCD L2 to the IF coherent point: coalescable, no RMW
//   serialization, NO buffer_wbl2/inv (Round-1's 12 us/step killer).
//   Ordering: __syncthreads() drains producer vmcnt (sc1 stores complete at
//   the coherent point) before the flag store; consumer loads issue only
//   after the flag poll. Parity-double-buffered hx: producer at t leads the
//   slowest consumer by <=1 step and writes the other parity; peer flag(t-1)
//   implies it consumed slot parity(t) -> overwrite is WAR-safe. Poisoned
//   d_ws = negative flags = clean initial state; flags monotone; no init.
//   Deadman spins: protocol failure -> bounded wrong answer, not a hang.

#define T_STEPS  4096
#define NBATCH   32
#define IN_DIM   128
#define HID      512
#define ALPHA    0.1f
#define NSCALE   0.05f
#define PT       64            // (t,b) rows per pre_kernel block

#define NSL          4         // row-slice blocks per group
#define SROWS        128       // W_hh rows per block
#define SCAN_BLOCKS  64        // 16 groups x 4 slices
#define SCAN_THREADS 512
#define RPT          4         // rows per thread
#define CPT          32        // cols per thread
#define NCT          16        // col-tiles (HID / CPT)
#define SPIN_MAX     (1 << 15)

// ---------------------------------------------------------------------------
__global__ __launch_bounds__(512, 2)
void pre_kernel(const float* __restrict__ x,      // [T][B][IN]
                const float* __restrict__ W_in,   // [H][IN]
                const float* __restrict__ b_in,   // [H]
                const float* __restrict__ b_hh,   // [H]
                const float* __restrict__ noise,  // [T][H]
                float* __restrict__ pre)          // [T][B][H] (= d_out)
{
    const int h = threadIdx.x;                    // 0..511
    const size_t row0 = (size_t)blockIdx.x * PT;  // flat (t*NBATCH+b) base

    float4 wr[32];
    const float4* wp = reinterpret_cast<const float4*>(&W_in[(size_t)h * IN_DIM]);
    #pragma unroll
    for (int q = 0; q < 32; ++q) wr[q] = wp[q];
    const float bc = b_in[h] + b_hh[h];

    __shared__ __align__(16) float xs[PT * IN_DIM];   // 32 KB
    {
        const float4* gx = reinterpret_cast<const float4*>(&x[row0 * IN_DIM]);
        float4* sx = reinterpret_cast<float4*>(xs);
        #pragma unroll
        for (int q = 0; q < 4; ++q) sx[q * 512 + h] = gx[q * 512 + h];
    }
    __syncthreads();

    #pragma unroll 1
    for (int rt = 0; rt < PT / NBATCH; ++rt) {        // 2 t-values per block
        const int t = (int)(row0 / NBATCH) + rt;
        const float add = fmaf(NSCALE, noise[(size_t)t * HID + h], bc);
        #pragma unroll 1
        for (int rb = 0; rb < NBATCH; ++rb) {
            const int r = rt * NBATCH + rb;
            const float4* xr = reinterpret_cast<const float4*>(&xs[r * IN_DIM]);
            float a0 = 0.f, a1 = 0.f, a2 = 0.f, a3 = 0.f;
            #pragma unroll
            for (int q = 0; q < 32; ++q) {            // wave-uniform broadcasts
                const float4 xv = xr[q];
                a0 = fmaf(wr[q].x, xv.x, a0);
                a1 = fmaf(wr[q].y, xv.y, a1);
                a2 = fmaf(wr[q].z, xv.z, a2);
                a3 = fmaf(wr[q].w, xv.w, a3);
            }
            pre[(row0 + r) * HID + h] = ((a0 + a1) + (a2 + a3)) + add;
        }
    }
}

// ---------------------------------------------------------------------------
__global__ __launch_bounds__(SCAN_THREADS, 2)
void rnn_scan(const float* __restrict__ W_hh,   // [H][H]
              float* __restrict__ out,          // [T][B][H]; pre on entry
              unsigned* __restrict__ hx,        // ws: [2][B][H] (f32 bits)
              int* __restrict__ flags)          // ws: [B][NSL]
{
    const int bx = blockIdx.x;
    // XCD-local grouping heuristic (bx&7 = XCD on round-robin dispatch);
    // correctness does NOT depend on placement — sc1 ops are coherent anywhere.
    const int c  = bx & 7;
    const int j  = bx >> 3;            // 0..7
    const int s  = j >> 1;             // row-slice 0..3
    const int g  = c * 2 + (j & 1);    // group 0..15
    const int b0 = 2 * g, b1 = 2 * g + 1;

    const int tid = threadIdx.x;
    const int w   = tid >> 6;          // wave 0..7
    const int l   = tid & 63;
    const int rt  = tid & 31;          // row-tile: local rows 4rt..4rt+3
    const int ct  = tid >> 5;          // col-tile: cols 32ct..32ct+31

    // W_hh[(128s + 4rt + i)][32ct .. 32ct+32), i=0..3 -> 32 float4 = 128 VGPR
    float4 wf[RPT][8];
    #pragma unroll
    for (int i = 0; i < RPT; ++i) {
        const float4* wp = reinterpret_cast<const float4*>(
            &W_hh[(size_t)(s * SROWS + RPT * rt + i) * HID + ct * CPT]);
        #pragma unroll
        for (int q = 0; q < 8; ++q) wf[i][q] = wp[q];
    }

    const int lr_own = (w << 6) + l;           // valid for w<2 (update role)
    const int r_own  = s * SROWS + lr_own;     // global row owned
    float hp0 = 0.f, hp1 = 0.f;

    __shared__ __align__(16) float h_lds[2][HID];
    __shared__ __align__(16) float part[2][NCT][SROWS];   // 16 KB

    h_lds[0][tid] = 0.f;
    h_lds[1][tid] = 0.f;
    __syncthreads();

    for (int t = 0; t < T_STEPS; ++t) {
        const int par = (t & 1) * NBATCH;

        // P: prefetch pre values (plain loads; overwritten later by SAME thread)
        float pv0 = 0.f, pv1 = 0.f;
        if (w < 2) {
            pv0 = out[((size_t)t * NBATCH + b0) * HID + r_own];
            pv1 = out[((size_t)t * NBATCH + b1) * HID + r_own];
        }

        // C0: partials for b0. Each thread: 8 b128 broadcast reads, 128 FMA.
        {
            const float4* hv4 = reinterpret_cast<const float4*>(&h_lds[0][ct * CPT]);
            float a0 = 0.f, a1 = 0.f, a2 = 0.f, a3 = 0.f;
            #pragma unroll
            for (int q = 0; q < 8; ++q) {
                const float4 h4 = hv4[q];
                a0 = fmaf(wf[0][q].x, h4.x, fmaf(wf[0][q].y, h4.y,
                     fmaf(wf[0][q].z, h4.z, fmaf(wf[0][q].w, h4.w, a0))));
                a1 = fmaf(wf[1][q].x, h4.x, fmaf(wf[1][q].y, h4.y,
                     fmaf(wf[1][q].z, h4.z, fmaf(wf[1][q].w, h4.w, a1))));
                a2 = fmaf(wf[2][q].x, h4.x, fmaf(wf[2][q].y, h4.y,
                     fmaf(wf[2][q].z, h4.z, fmaf(wf[2][q].w, h4.w, a2))));
                a3 = fmaf(wf[3][q].x, h4.x, fmaf(wf[3][q].y, h4.y,
                     fmaf(wf[3][q].z, h4.z, fmaf(wf[3][q].w, h4.w, a3))));
            }
            *reinterpret_cast<float4*>(&part[0][ct][RPT * rt]) =
                make_float4(a0, a1, a2, a3);   // contiguous b128, conflict-free
        }
        __syncthreads();                                   // B1

        // U0 (waves 0-1) + C1 (all waves)
        if (w < 2) {
            float tot = 0.f;
            #pragma unroll
            for (int q = 0; q < NCT; ++q)
                tot += part[0][q][lr_own];     // lane-stride-1, 2-way = free
            float hn = fmaf(1.f - ALPHA, hp0, ALPHA * (tot + pv0));
            hn = fmaxf(hn, 0.f);
            hp0 = hn;
            out[((size_t)t * NBATCH + b0) * HID + r_own] = hn;
            h_lds[0][r_own] = hn;                          // own slice, local
            __hip_atomic_store(&hx[(size_t)(par + b0) * HID + r_own],
                               __float_as_uint(hn),
                               __ATOMIC_RELAXED, __HIP_MEMORY_SCOPE_AGENT);
        }
        {
            const float4* hv4 = reinterpret_cast<const float4*>(&h_lds[1][ct * CPT]);
            float a0 = 0.f, a1 = 0.f, a2 = 0.f, a3 = 0.f;
            #pragma unroll
            for (int q = 0; q < 8; ++q) {
                const float4 h4 = hv4[q];
                a0 = fmaf(wf[0][q].x, h4.x, fmaf(wf[0][q].y, h4.y,
                     fmaf(wf[0][q].z, h4.z, fmaf(wf[0][q].w, h4.w, a0))));
                a1 = fmaf(wf[1][q].x, h4.x, fmaf(wf[1][q].y, h4.y,
                     fmaf(wf[1][q].z, h4.z, fmaf(wf[1][q].w, h4.w, a1))));
                a2 = fmaf(wf[2][q].x, h4.x, fmaf(wf[2][q].y, h4.y,
                     fmaf(wf[2][q].z, h4.z, fmaf(wf[2][q].w, h4.w, a2))));
                a3 = fmaf(wf[3][q].x, h4.x, fmaf(wf[3][q].y, h4.y,
                     fmaf(wf[3][q].z, h4.z, fmaf(wf[3][q].w, h4.w, a3))));
            }
            *reinterpret_cast<float4*>(&part[1][ct][RPT * rt]) =
                make_float4(a0, a1, a2, a3);
        }
        __syncthreads();               // B2 — vmcnt(0) drain: b0 stores at IF

        if (tid == 0)                  // F0: publish b0 flag
            __hip_atomic_store(&flags[b0 * NSL + s], t,
                               __ATOMIC_RELAXED, __HIP_MEMORY_SCOPE_AGENT);
        // U1 (waves 0-1)
        if (w < 2) {
            float tot = 0.f;
            #pragma unroll
            for (int q = 0; q < NCT; ++q)
                tot += part[1][q][lr_own];
            float hn = fmaf(1.f - ALPHA, hp1, ALPHA * (tot + pv1));
            hn = fmaxf(hn, 0.f);
            hp1 = hn;
            out[((size_t)t * NBATCH + b1) * HID + r_own] = hn;
            h_lds[1][r_own] = hn;
            __hip_atomic_store(&hx[(size_t)(par + b1) * HID + r_own],
                               __float_as_uint(hn),
                               __ATOMIC_RELAXED, __HIP_MEMORY_SCOPE_AGENT);
        }
        // S0: wave 2 spins for b0 peers (sc1 load = coherent-point read)
        if (w == 2 && l < NSL && l != s) {
            int dm = 0, v;
            do {
                v = __hip_atomic_load(&flags[b0 * NSL + l],
                                      __ATOMIC_RELAXED, __HIP_MEMORY_SCOPE_AGENT);
            } while (v < t && ++dm < SPIN_MAX);
        }
        __syncthreads();               // B3 — b1 stores at IF; b0 flags seen

        if (tid == 0)                  // F1: publish b1 flag
            __hip_atomic_store(&flags[b1 * NSL + s], t,
                               __ATOMIC_RELAXED, __HIP_MEMORY_SCOPE_AGENT);
        // L0: fetch b0's remote h_t (own slice already in LDS); coalesced sc1
        if ((tid >> 7) != s) {
            const unsigned uv = __hip_atomic_load(
                &hx[(size_t)(par + b0) * HID + tid],
                __ATOMIC_RELAXED, __HIP_MEMORY_SCOPE_AGENT);
            h_lds[0][tid] = __uint_as_float(uv);
        }
        // S1: spin for b1 peers (overlaps L0's in-flight loads)
        if (w == 2 && l < NSL && l != s) {
            int dm = 0, v;
            do {
                v = __hip_atomic_load(&flags[b1 * NSL + l],
                                      __ATOMIC_RELAXED, __HIP_MEMORY_SCOPE_AGENT);
            } while (v < t && ++dm < SPIN_MAX);
        }
        __syncthreads();               // B4 — h_lds[0] ready; b1 flags seen

        // L1: fetch b1's remote h_t. No barrier needed after: next step's C0
        // only touches h_lds[0]; B1 (before C1) protects h_lds[1].
        if ((tid >> 7) != s) {
            const unsigned uv = __hip_atomic_load(
                &hx[(size_t)(par + b1) * HID + tid],
                __ATOMIC_RELAXED, __HIP_MEMORY_SCOPE_AGENT);
            h_lds[1][tid] = __uint_as_float(uv);
        }
    }
}

// ---------------------------------------------------------------------------
extern "C" void kernel_launch(void* const* d_in, const int* in_sizes, int n_in,
                              void* d_out, int out_size, void* d_ws, size_t ws_size,
                              hipStream_t stream) {
    (void)in_sizes; (void)n_in; (void)out_size; (void)ws_size;
    const float* x     = (const float*)d_in[0];
    const float* W_in  = (const float*)d_in[1];
    const float* b_in  = (const float*)d_in[2];
    const float* W_hh  = (const float*)d_in[3];
    const float* b_hh  = (const float*)d_in[4];
    const float* noise = (const float*)d_in[5];
    float* out = (float*)d_out;

    unsigned* hx  = (unsigned*)d_ws;                            // 2*32*512 u32
    int*      flg = (int*)((char*)d_ws + 2 * NBATCH * HID * 4); // 32*4 ints

    hipLaunchKernelGGL(pre_kernel, dim3((T_STEPS * NBATCH) / PT), dim3(512),
                       0, stream, x, W_in, b_in, b_hh, noise, out);
    hipLaunchKernelGGL(rnn_scan, dim3(SCAN_BLOCKS), dim3(SCAN_THREADS),
                       0, stream, W_hh, out, hx, flg);
}

// Round 7
// 9548.549 us; speedup vs baseline: 5.2413x; 1.4393x over previous
//
#include <hip/hip_runtime.h>

// Leaky-RNN scan: h_t = relu(0.9 h + 0.1 (W_hh h + W_in x_t + b_in + b_hh + 0.05 nz_t))
// T=4096, B=32, IN=128, H=512, fp32.
//
// pre_kernel: pre[t][b][h] = W_in·x + b_in + b_hh + 0.05*noise, IN-PLACE into
//   d_out (time-parallel, all CUs, ~150 us).
// rnn_scan: 16 groups x 4 row-slice blocks (64 blocks x 512 thr, 1 block/CU).
//   fp32 W_hh (1 MB) cannot fit one CU's 512 KB register file -> 4-CU
//   row-split. Per-thread W tile = 4 rows x 32 cols (128 regs, AGPR-backed).
//
// Round-7 change (from measured 7200 cy/step, ~5300 cy exchange-exposed):
//   SELF-SIGNALING EXCHANGE. hx is u64 = (epoch<<32)|h_bits, published by ONE
//   relaxed agent-scope 8-byte atomic store (global_store_dwordx2 sc1, single-
//   copy atomic, IF-coherent — protocol validated on HW in Round 6). Consumers
//   poll their own word until epoch==t: the data load IS the readiness flag.
//   Removes flag stores, flag spins, and the drain-before-flag ordering —
//   ~2 fewer IF round trips and one fewer barrier (3/step).
//   WAR safety: parity double-buffer + dependency chain. To publish t+1 I need
//   all peers' t; to publish t+2 (same parity slot as t) I need peers' t+1,
//   which peers publish only after consuming my t -> overwrite-safe. Poisoned
//   d_ws => epoch 0xAAAAAAAA matches no t in [0,4096) => clean initial state.
//   Deadman-bounded polls: failure -> bounded wrong answer, not a hang.

#define T_STEPS  4096
#define NBATCH   32
#define IN_DIM   128
#define HID      512
#define ALPHA    0.1f
#define NSCALE   0.05f
#define PT       64            // (t,b) rows per pre_kernel block

#define NSL          4         // row-slice blocks per group
#define SROWS        128       // W_hh rows per block
#define SCAN_BLOCKS  64        // 16 groups x 4 slices
#define SCAN_THREADS 512
#define RPT          4         // rows per thread
#define CPT          32        // cols per thread
#define NCT          16        // col-tiles (HID / CPT)
#define SPIN_MAX     (1 << 15)

// ---------------------------------------------------------------------------
__global__ __launch_bounds__(512, 2)
void pre_kernel(const float* __restrict__ x,      // [T][B][IN]
                const float* __restrict__ W_in,   // [H][IN]
                const float* __restrict__ b_in,   // [H]
                const float* __restrict__ b_hh,   // [H]
                const float* __restrict__ noise,  // [T][H]
                float* __restrict__ pre)          // [T][B][H] (= d_out)
{
    const int h = threadIdx.x;                    // 0..511
    const size_t row0 = (size_t)blockIdx.x * PT;  // flat (t*NBATCH+b) base

    float4 wr[32];
    const float4* wp = reinterpret_cast<const float4*>(&W_in[(size_t)h * IN_DIM]);
    #pragma unroll
    for (int q = 0; q < 32; ++q) wr[q] = wp[q];
    const float bc = b_in[h] + b_hh[h];

    __shared__ __align__(16) float xs[PT * IN_DIM];   // 32 KB
    {
        const float4* gx = reinterpret_cast<const float4*>(&x[row0 * IN_DIM]);
        float4* sx = reinterpret_cast<float4*>(xs);
        #pragma unroll
        for (int q = 0; q < 4; ++q) sx[q * 512 + h] = gx[q * 512 + h];
    }
    __syncthreads();

    #pragma unroll 1
    for (int rt = 0; rt < PT / NBATCH; ++rt) {        // 2 t-values per block
        const int t = (int)(row0 / NBATCH) + rt;
        const float add = fmaf(NSCALE, noise[(size_t)t * HID + h], bc);
        #pragma unroll 1
        for (int rb = 0; rb < NBATCH; ++rb) {
            const int r = rt * NBATCH + rb;
            const float4* xr = reinterpret_cast<const float4*>(&xs[r * IN_DIM]);
            float a0 = 0.f, a1 = 0.f, a2 = 0.f, a3 = 0.f;
            #pragma unroll
            for (int q = 0; q < 32; ++q) {            // wave-uniform broadcasts
                const float4 xv = xr[q];
                a0 = fmaf(wr[q].x, xv.x, a0);
                a1 = fmaf(wr[q].y, xv.y, a1);
                a2 = fmaf(wr[q].z, xv.z, a2);
                a3 = fmaf(wr[q].w, xv.w, a3);
            }
            pre[(row0 + r) * HID + h] = ((a0 + a1) + (a2 + a3)) + add;
        }
    }
}

// ---------------------------------------------------------------------------
__global__ __launch_bounds__(SCAN_THREADS, 2)
void rnn_scan(const float* __restrict__ W_hh,          // [H][H]
              float* __restrict__ out,                 // [T][B][H]; pre on entry
              unsigned long long* __restrict__ hx)     // ws: [2][B][H] u64
{
    const int bx = blockIdx.x;
    // XCD-local grouping heuristic (bx&7 = XCD on round-robin dispatch);
    // correctness does NOT depend on placement — sc1 ops are coherent anywhere.
    const int c  = bx & 7;
    const int j  = bx >> 3;            // 0..7
    const int s  = j >> 1;             // row-slice 0..3
    const int g  = c * 2 + (j & 1);    // group 0..15
    const int b0 = 2 * g, b1 = 2 * g + 1;

    const int tid = threadIdx.x;
    const int w   = tid >> 6;          // wave 0..7
    const int l   = tid & 63;
    const int rt  = tid & 31;          // row-tile: local rows 4rt..4rt+3
    const int ct  = tid >> 5;          // col-tile: cols 32ct..32ct+31

    // W_hh[(128s + 4rt + i)][32ct .. 32ct+32), i=0..3 -> 32 float4 = 128 regs
    float4 wf[RPT][8];
    #pragma unroll
    for (int i = 0; i < RPT; ++i) {
        const float4* wp = reinterpret_cast<const float4*>(
            &W_hh[(size_t)(s * SROWS + RPT * rt + i) * HID + ct * CPT]);
        #pragma unroll
        for (int q = 0; q < 8; ++q) wf[i][q] = wp[q];
    }

    const int lr_own = (w << 6) + l;           // valid for w<2 (update role)
    const int r_own  = s * SROWS + lr_own;     // global row owned
    const bool remote = (tid >> 7) != s;       // this tid's h-word is remote
    float hp0 = 0.f, hp1 = 0.f;

    __shared__ __align__(16) float h_lds[2][HID];
    __shared__ __align__(16) float part[2][NCT][SROWS];   // 16 KB

    h_lds[0][tid] = 0.f;
    h_lds[1][tid] = 0.f;
    __syncthreads();

    for (int t = 0; t < T_STEPS; ++t) {
        const int par = (t & 1) * NBATCH;

        // P: prefetch pre values (plain loads; overwritten later by SAME thread)
        float pv0 = 0.f, pv1 = 0.f;
        if (w < 2) {
            pv0 = out[((size_t)t * NBATCH + b0) * HID + r_own];
            pv1 = out[((size_t)t * NBATCH + b1) * HID + r_own];
        }

        // C0: partials for b0. Each thread: 8 b128 broadcast reads, 128 FMA.
        {
            const float4* hv4 = reinterpret_cast<const float4*>(&h_lds[0][ct * CPT]);
            float a0 = 0.f, a1 = 0.f, a2 = 0.f, a3 = 0.f;
            #pragma unroll
            for (int q = 0; q < 8; ++q) {
                const float4 h4 = hv4[q];
                a0 = fmaf(wf[0][q].x, h4.x, fmaf(wf[0][q].y, h4.y,
                     fmaf(wf[0][q].z, h4.z, fmaf(wf[0][q].w, h4.w, a0))));
                a1 = fmaf(wf[1][q].x, h4.x, fmaf(wf[1][q].y, h4.y,
                     fmaf(wf[1][q].z, h4.z, fmaf(wf[1][q].w, h4.w, a1))));
                a2 = fmaf(wf[2][q].x, h4.x, fmaf(wf[2][q].y, h4.y,
                     fmaf(wf[2][q].z, h4.z, fmaf(wf[2][q].w, h4.w, a2))));
                a3 = fmaf(wf[3][q].x, h4.x, fmaf(wf[3][q].y, h4.y,
                     fmaf(wf[3][q].z, h4.z, fmaf(wf[3][q].w, h4.w, a3))));
            }
            *reinterpret_cast<float4*>(&part[0][ct][RPT * rt]) =
                make_float4(a0, a1, a2, a3);   // contiguous b128, conflict-free
        }
        __syncthreads();                                   // B1

        // U0 (waves 0-1: finish b0, publish self-signaling word) + C1 (all)
        if (w < 2) {
            float tot = 0.f;
            #pragma unroll
            for (int q = 0; q < NCT; ++q)
                tot += part[0][q][lr_own];     // lane-stride-1, 2-way = free
            float hn = fmaf(1.f - ALPHA, hp0, ALPHA * (tot + pv0));
            hn = fmaxf(hn, 0.f);
            hp0 = hn;
            out[((size_t)t * NBATCH + b0) * HID + r_own] = hn;
            h_lds[0][r_own] = hn;                          // own slice, local
            const unsigned long long pk =
                ((unsigned long long)(unsigned)t << 32) |
                (unsigned long long)__float_as_uint(hn);
            __hip_atomic_store(&hx[(size_t)(par + b0) * HID + r_own], pk,
                               __ATOMIC_RELAXED, __HIP_MEMORY_SCOPE_AGENT);
        }
        {
            const float4* hv4 = reinterpret_cast<const float4*>(&h_lds[1][ct * CPT]);
            float a0 = 0.f, a1 = 0.f, a2 = 0.f, a3 = 0.f;
            #pragma unroll
            for (int q = 0; q < 8; ++q) {
                const float4 h4 = hv4[q];
                a0 = fmaf(wf[0][q].x, h4.x, fmaf(wf[0][q].y, h4.y,
                     fmaf(wf[0][q].z, h4.z, fmaf(wf[0][q].w, h4.w, a0))));
                a1 = fmaf(wf[1][q].x, h4.x, fmaf(wf[1][q].y, h4.y,
                     fmaf(wf[1][q].z, h4.z, fmaf(wf[1][q].w, h4.w, a1))));
                a2 = fmaf(wf[2][q].x, h4.x, fmaf(wf[2][q].y, h4.y,
                     fmaf(wf[2][q].z, h4.z, fmaf(wf[2][q].w, h4.w, a2))));
                a3 = fmaf(wf[3][q].x, h4.x, fmaf(wf[3][q].y, h4.y,
                     fmaf(wf[3][q].z, h4.z, fmaf(wf[3][q].w, h4.w, a3))));
            }
            *reinterpret_cast<float4*>(&part[1][ct][RPT * rt]) =
                make_float4(a0, a1, a2, a3);
        }
        __syncthreads();                                   // B2

        // U1 (waves 0-1: finish b1, publish) + L0 (remote tids: poll b0's h_t)
        if (w < 2) {
            float tot = 0.f;
            #pragma unroll
            for (int q = 0; q < NCT; ++q)
                tot += part[1][q][lr_own];
            float hn = fmaf(1.f - ALPHA, hp1, ALPHA * (tot + pv1));
            hn = fmaxf(hn, 0.f);
            hp1 = hn;
            out[((size_t)t * NBATCH + b1) * HID + r_own] = hn;
            h_lds[1][r_own] = hn;
            const unsigned long long pk =
                ((unsigned long long)(unsigned)t << 32) |
                (unsigned long long)__float_as_uint(hn);
            __hip_atomic_store(&hx[(size_t)(par + b1) * HID + r_own], pk,
                               __ATOMIC_RELAXED, __HIP_MEMORY_SCOPE_AGENT);
        }
        if (remote && t + 1 < T_STEPS) {
            unsigned long long v;
            int dm = 0;
            do {
                v = __hip_atomic_load(&hx[(size_t)(par + b0) * HID + tid],
                                      __ATOMIC_RELAXED, __HIP_MEMORY_SCOPE_AGENT);
            } while ((unsigned)(v >> 32) != (unsigned)t && ++dm < SPIN_MAX);
            h_lds[0][tid] = __uint_as_float((unsigned)v);
        }
        __syncthreads();                                   // B3

        // L1: poll b1's remote h_t. No barrier after: next C0 reads h_lds[0]
        // (written in L0/U0, before B3); h_lds[1] is consumed after next B1.
        if (remote && t + 1 < T_STEPS) {
            unsigned long long v;
            int dm = 0;
            do {
                v = __hip_atomic_load(&hx[(size_t)(par + b1) * HID + tid],
                                      __ATOMIC_RELAXED, __HIP_MEMORY_SCOPE_AGENT);
            } while ((unsigned)(v >> 32) != (unsigned)t && ++dm < SPIN_MAX);
            h_lds[1][tid] = __uint_as_float((unsigned)v);
        }
    }
}

// ---------------------------------------------------------------------------
extern "C" void kernel_launch(void* const* d_in, const int* in_sizes, int n_in,
                              void* d_out, int out_size, void* d_ws, size_t ws_size,
                              hipStream_t stream) {
    (void)in_sizes; (void)n_in; (void)out_size; (void)ws_size;
    const float* x     = (const float*)d_in[0];
    const float* W_in  = (const float*)d_in[1];
    const float* b_in  = (const float*)d_in[2];
    const float* W_hh  = (const float*)d_in[3];
    const float* b_hh  = (const float*)d_in[4];
    const float* noise = (const float*)d_in[5];
    float* out = (float*)d_out;

    unsigned long long* hx = (unsigned long long*)d_ws;   // [2][32][512] u64 = 256 KB

    hipLaunchKernelGGL(pre_kernel, dim3((T_STEPS * NBATCH) / PT), dim3(512),
                       0, stream, x, W_in, b_in, b_hh, noise, out);
    hipLaunchKernelGGL(rnn_scan, dim3(SCAN_BLOCKS), dim3(SCAN_THREADS),
                       0, stream, W_hh, out, hx);
}

// Round 8
// 6536.861 us; speedup vs baseline: 7.6560x; 1.4607x over previous
//
#include <hip/hip_runtime.h>

// Leaky-RNN scan: h_t = relu(0.9 h + 0.1 (W_hh h + W_in x_t + b_in + b_hh + 0.05 nz_t))
// T=4096, B=32, IN=128, H=512, fp32.
//
// pre_kernel (unchanged, proven): pre[t][b][h] = W_in·x + b_in + b_hh +
//   0.05*noise, IN-PLACE into d_out (time-parallel, all CUs, ~150 us).
//
// rnn_scan Round-8: 32 groups (one per batch) x 8 row-slice blocks
//   = 256 blocks x 512 thr -> ALL CUs, 1 block/CU. Measured R7: step was
//   4650 cy with ~2800 cy exposed IF-poll latency; serial chain is
//   publish -> propagate -> poll -> GEMV, so shrink the GEMV term 4x by
//   splitting rows 8 ways (64 rows/block, W = 64 VGPR/thread, RPT=4 x CPT=16).
//   Roles per step: wave 0 = update+publish its 64 rows; waves 1-7 each poll
//   exactly one remote row-word (7x64 = 448) concurrently. 2 barriers/step.
//   Exchange: self-signaling u64 hx word = (epoch<<32)|h_bits via relaxed
//   AGENT-scope 8B atomic store/load (sc1, IF-coherent, single-copy atomic —
//   HW-validated R6/R7). Data load IS the readiness flag. Parity double
//   buffer: publishing t+2 (same slot as t) requires consuming peers' t+1,
//   which peers publish only after consuming my t -> WAR-safe. Poisoned d_ws
//   epoch 0xAAAAAAAA matches no t in [0,4096) -> clean initial state.
//   Deadman polls: protocol failure -> bounded wrong answer, not a hang.
//   XCD heuristic: bx&7 = XCD residue on round-robin dispatch; the 8 slices
//   of a group share it. Perf-only — sc1 is coherent regardless of placement.

#define T_STEPS  4096
#define NBATCH   32
#define IN_DIM   128
#define HID      512
#define ALPHA    0.1f
#define NSCALE   0.05f
#define PT       64            // (t,b) rows per pre_kernel block

#define NSL          8         // row-slice blocks per group
#define SROWS        64        // W_hh rows per block
#define SCAN_BLOCKS  256       // 32 groups x 8 slices = all CUs
#define SCAN_THREADS 512
#define RPT          4         // rows per thread
#define CPT          16        // cols per thread
#define SPIN_MAX     (1 << 15)

// ---------------------------------------------------------------------------
__global__ __launch_bounds__(512, 2)
void pre_kernel(const float* __restrict__ x,      // [T][B][IN]
                const float* __restrict__ W_in,   // [H][IN]
                const float* __restrict__ b_in,   // [H]
                const float* __restrict__ b_hh,   // [H]
                const float* __restrict__ noise,  // [T][H]
                float* __restrict__ pre)          // [T][B][H] (= d_out)
{
    const int h = threadIdx.x;                    // 0..511
    const size_t row0 = (size_t)blockIdx.x * PT;  // flat (t*NBATCH+b) base

    float4 wr[32];
    const float4* wp = reinterpret_cast<const float4*>(&W_in[(size_t)h * IN_DIM]);
    #pragma unroll
    for (int q = 0; q < 32; ++q) wr[q] = wp[q];
    const float bc = b_in[h] + b_hh[h];

    __shared__ __align__(16) float xs[PT * IN_DIM];   // 32 KB
    {
        const float4* gx = reinterpret_cast<const float4*>(&x[row0 * IN_DIM]);
        float4* sx = reinterpret_cast<float4*>(xs);
        #pragma unroll
        for (int q = 0; q < 4; ++q) sx[q * 512 + h] = gx[q * 512 + h];
    }
    __syncthreads();

    #pragma unroll 1
    for (int rt = 0; rt < PT / NBATCH; ++rt) {        // 2 t-values per block
        const int t = (int)(row0 / NBATCH) + rt;
        const float add = fmaf(NSCALE, noise[(size_t)t * HID + h], bc);
        #pragma unroll 1
        for (int rb = 0; rb < NBATCH; ++rb) {
            const int r = rt * NBATCH + rb;
            const float4* xr = reinterpret_cast<const float4*>(&xs[r * IN_DIM]);
            float a0 = 0.f, a1 = 0.f, a2 = 0.f, a3 = 0.f;
            #pragma unroll
            for (int q = 0; q < 32; ++q) {            // wave-uniform broadcasts
                const float4 xv = xr[q];
                a0 = fmaf(wr[q].x, xv.x, a0);
                a1 = fmaf(wr[q].y, xv.y, a1);
                a2 = fmaf(wr[q].z, xv.z, a2);
                a3 = fmaf(wr[q].w, xv.w, a3);
            }
            pre[(row0 + r) * HID + h] = ((a0 + a1) + (a2 + a3)) + add;
        }
    }
}

// ---------------------------------------------------------------------------
__global__ __launch_bounds__(SCAN_THREADS, 2)
void rnn_scan(const float* __restrict__ W_hh,          // [H][H]
              float* __restrict__ out,                 // [T][B][H]; pre on entry
              unsigned long long* __restrict__ hx)     // ws: [2][B][H] u64
{
    const int bx = blockIdx.x;
    const int c  = bx & 7;             // XCD residue (placement heuristic only)
    const int j  = bx >> 3;            // 0..31
    const int s  = j & 7;              // row-slice 0..7
    const int b  = c * 4 + (j >> 3);   // group == batch 0..31

    const int tid = threadIdx.x;
    const int w   = tid >> 6;          // wave 0..7
    const int l   = tid & 63;          // lane
    const int rt  = tid & 15;          // row-tile: local rows 4rt..4rt+3
    const int ct  = tid >> 4;          // col-tile 0..31: cols [16ct,16ct+16)

    // W_hh[(64s + 4rt + i)][16ct .. 16ct+16), i=0..3 -> 16 float4 = 64 VGPR
    float4 wf[RPT][4];
    #pragma unroll
    for (int i = 0; i < RPT; ++i) {
        const float4* wp = reinterpret_cast<const float4*>(
            &W_hh[(size_t)(s * SROWS + RPT * rt + i) * HID + ct * CPT]);
        #pragma unroll
        for (int q = 0; q < 4; ++q) wf[i][q] = wp[q];
    }

    const int r_own = s * SROWS + l;           // update role (wave 0): global row
    const int rp = ((s + w) & 7) * SROWS + l;  // poll role (waves 1-7): remote row
    float hprev = 0.f;

    __shared__ __align__(16) float h_lds[HID];         // full h_{t-1}
    __shared__ float part2[NSL][SROWS];                // per-wave row partials

    h_lds[tid] = 0.f;
    __syncthreads();

    for (int t = 0; t < T_STEPS; ++t) {
        const size_t hxbase = (size_t)((t & 1) * NBATCH + b) * HID;

        // prefetch pre (plain load; SAME thread overwrites this addr later)
        float pv = 0.f;
        if (w == 0) pv = out[((size_t)t * NBATCH + b) * HID + r_own];

        // C: 64 FMA/thread; h reads are 4x b128, 4 addrs/wave, 2-way alias = free
        const float4* hp = reinterpret_cast<const float4*>(&h_lds[ct * CPT]);
        float a0 = 0.f, a1 = 0.f, a2 = 0.f, a3 = 0.f;
        #pragma unroll
        for (int q = 0; q < 4; ++q) {
            const float4 h4 = hp[q];
            a0 = fmaf(wf[0][q].x, h4.x, fmaf(wf[0][q].y, h4.y,
                 fmaf(wf[0][q].z, h4.z, fmaf(wf[0][q].w, h4.w, a0))));
            a1 = fmaf(wf[1][q].x, h4.x, fmaf(wf[1][q].y, h4.y,
                 fmaf(wf[1][q].z, h4.z, fmaf(wf[1][q].w, h4.w, a1))));
            a2 = fmaf(wf[2][q].x, h4.x, fmaf(wf[2][q].y, h4.y,
                 fmaf(wf[2][q].z, h4.z, fmaf(wf[2][q].w, h4.w, a2))));
            a3 = fmaf(wf[3][q].x, h4.x, fmaf(wf[3][q].y, h4.y,
                 fmaf(wf[3][q].z, h4.z, fmaf(wf[3][q].w, h4.w, a3))));
        }
        // in-wave reduce across this wave's 4 col-tile lane-groups
        a0 += __shfl_xor(a0, 16, 64);  a0 += __shfl_xor(a0, 32, 64);
        a1 += __shfl_xor(a1, 16, 64);  a1 += __shfl_xor(a1, 32, 64);
        a2 += __shfl_xor(a2, 16, 64);  a2 += __shfl_xor(a2, 32, 64);
        a3 += __shfl_xor(a3, 16, 64);  a3 += __shfl_xor(a3, 32, 64);
        if (l < 16) {                   // lane l == rt here
            part2[w][4 * l + 0] = a0;
            part2[w][4 * l + 1] = a1;
            part2[w][4 * l + 2] = a2;
            part2[w][4 * l + 3] = a3;
        }
        __syncthreads();                                   // B1

        if (w == 0) {
            // U: reduce 8 per-wave partials, update, publish self-signaling word
            float tot = 0.f;
            #pragma unroll
            for (int k = 0; k < NSL; ++k)
                tot += part2[k][l];        // lane-stride-1, 2-way alias = free
            float hn = fmaf(1.f - ALPHA, hprev, ALPHA * (tot + pv));
            hn = fmaxf(hn, 0.f);
            hprev = hn;
            out[((size_t)t * NBATCH + b) * HID + r_own] = hn;
            h_lds[r_own] = hn;
            const unsigned long long pk =
                ((unsigned long long)(unsigned)t << 32) |
                (unsigned long long)__float_as_uint(hn);
            __hip_atomic_store(&hx[hxbase + r_own], pk,
                               __ATOMIC_RELAXED, __HIP_MEMORY_SCOPE_AGENT);
        } else if (t + 1 < T_STEPS) {
            // P: poll my one remote word until its epoch == t (data IS flag)
            unsigned long long v;
            int dm = 0;
            do {
                v = __hip_atomic_load(&hx[hxbase + rp],
                                      __ATOMIC_RELAXED, __HIP_MEMORY_SCOPE_AGENT);
            } while ((unsigned)(v >> 32) != (unsigned)t && ++dm < SPIN_MAX);
            h_lds[rp] = __uint_as_float((unsigned)v);
        }
        __syncthreads();                                   // B2
    }
}

// ---------------------------------------------------------------------------
extern "C" void kernel_launch(void* const* d_in, const int* in_sizes, int n_in,
                              void* d_out, int out_size, void* d_ws, size_t ws_size,
                              hipStream_t stream) {
    (void)in_sizes; (void)n_in; (void)out_size; (void)ws_size;
    const float* x     = (const float*)d_in[0];
    const float* W_in  = (const float*)d_in[1];
    const float* b_in  = (const float*)d_in[2];
    const float* W_hh  = (const float*)d_in[3];
    const float* b_hh  = (const float*)d_in[4];
    const float* noise = (const float*)d_in[5];
    float* out = (float*)d_out;

    unsigned long long* hx = (unsigned long long*)d_ws;   // [2][32][512] u64 = 256 KB

    hipLaunchKernelGGL(pre_kernel, dim3((T_STEPS * NBATCH) / PT), dim3(512),
                       0, stream, x, W_in, b_in, b_hh, noise, out);
    hipLaunchKernelGGL(rnn_scan, dim3(SCAN_BLOCKS), dim3(SCAN_THREADS),
                       0, stream, W_hh, out, hx);
}